// Round 4
// baseline (284.634 us; speedup 1.0000x reference)
//
#include <hip/hip_runtime.h>

// B=1048576, A=3, N=8, NUM_CLASSES=3, LAMBDA_COORD=5
#define B_SIZE 1048576
#define TPB    1024              // 16 waves/block -> 4x fewer workgroups than R1-R3
#define NBLK   (B_SIZE / TPB)    // 1024 workgroups

__device__ __forceinline__ float frcp(float x) { return __builtin_amdgcn_rcpf(x); }

__global__ __launch_bounds__(TPB) void yolo_loss_kernel(
    const float* __restrict__ pred,       // [B,3,8]  row = 24 floats
    const float* __restrict__ gt_boxes,   // [B,8,4]  row = 32 floats
    const int*   __restrict__ gt_classes, // [B,8]    row = 8 ints
    double* __restrict__ part) {          // [NBLK] per-block partials
    const int tid = threadIdx.x;
    const int b   = blockIdx.x * TPB + tid;   // grid covers B exactly

    // ---- direct per-thread loads (R3 proved these don't over-fetch) ----
    float pr[24];
    const float4* pv4 = reinterpret_cast<const float4*>(pred + (size_t)b * 24);
    #pragma unroll
    for (int i = 0; i < 6; ++i) reinterpret_cast<float4*>(pr)[i] = pv4[i];

    float gb[32];
    const float4* gv4 = reinterpret_cast<const float4*>(gt_boxes + (size_t)b * 32);
    #pragma unroll
    for (int i = 0; i < 8; ++i) reinterpret_cast<float4*>(gb)[i] = gv4[i];

    int gc[8];
    const int4* gc4 = reinterpret_cast<const int4*>(gt_classes + (size_t)b * 8);
    #pragma unroll
    for (int i = 0; i < 2; ++i) reinterpret_cast<int4*>(gc)[i] = gc4[i];

    // ---- per-anchor loss math (validated R2) ----
    float total = 0.0f;
    #pragma unroll
    for (int a = 0; a < 3; ++a) {
        const float* p = pr + a * 8;
        const float px = frcp(1.0f + __expf(-p[0]));
        const float py = frcp(1.0f + __expf(-p[1]));
        const float pw = p[2];
        const float ph = p[3];
        const float z  = p[4];
        const float px1 = px - pw * 0.5f, px2 = px + pw * 0.5f;
        const float py1 = py - ph * 0.5f, py2 = py + ph * 0.5f;
        const float pa_eps = (px2 - px1) * (py2 - py1) + 1e-6f;

        float best_iou = -3.4e38f;
        int best_idx = 0;
        #pragma unroll
        for (int n = 0; n < 8; ++n) {
            const float gx = gb[n*4+0], gy = gb[n*4+1];
            const float gw = gb[n*4+2], gh = gb[n*4+3];
            const float hw = gw * 0.5f, hh = gh * 0.5f;
            const float iw = fmaxf(fminf(px2, gx + hw) - fmaxf(px1, gx - hw), 0.0f);
            const float ih = fmaxf(fminf(py2, gy + hh) - fmaxf(py1, gy - hh), 0.0f);
            const float inter = iw * ih;
            const float iou = inter * frcp((pa_eps + gw * gh) - inter);
            const bool upd = iou > best_iou;       // strict > == first-max (argmax)
            best_iou = upd ? iou : best_iou;
            best_idx = upd ? n : best_idx;
        }
        const bool matched = best_iou > 0.5f;

        float mbx = gb[0], mby = gb[1], mbw = gb[2], mbh = gb[3];
        int mcls = gc[0];
        #pragma unroll
        for (int n = 1; n < 8; ++n) {
            const bool s = (best_idx == n);
            mbx = s ? gb[n*4+0] : mbx;
            mby = s ? gb[n*4+1] : mby;
            mbw = s ? gb[n*4+2] : mbw;
            mbh = s ? gb[n*4+3] : mbh;
            mcls = s ? gc[n] : mcls;
        }

        // conf loss via shared softplus (clamped at 100):
        const float az = fabsf(z);
        const float c  = __logf(1.0f + __expf(-az));
        const float sp_pos = fmaxf(z, 0.0f) + c;
        const float sp_neg = fmaxf(-z, 0.0f) + c;
        total += fminf(matched ? sp_neg : sp_pos, 100.0f);

        if (matched) {
            const float dx = px - mbx, dy = py - mby;
            const float dw = pw - mbw, dh = ph - mbh;
            total += 5.0f * (dx*dx + dy*dy + dw*dw + dh*dh);
            const float l0 = p[5], l1 = p[6], l2 = p[7];
            const float m = fmaxf(l0, fmaxf(l1, l2));
            const float lse = m + __logf(__expf(l0-m) + __expf(l1-m) + __expf(l2-m));
            const float sel = (mcls == 0) ? l0 : ((mcls == 1) ? l1 : l2);
            total += lse - sel;
        }
    }

    // ---- wave(64) shuffle reduce -> LDS -> per-block partial store ----
    #pragma unroll
    for (int off = 32; off > 0; off >>= 1)
        total += __shfl_down(total, off, 64);
    __shared__ float smem[16];
    const int lane = tid & 63;
    const int wid  = tid >> 6;
    if (lane == 0) smem[wid] = total;
    __syncthreads();
    if (tid == 0) {
        double s = 0.0;
        #pragma unroll
        for (int w = 0; w < 16; ++w) s += (double)smem[w];
        part[blockIdx.x] = s;
    }
}

__global__ __launch_bounds__(256) void yolo_reduce_kernel(
    const double* __restrict__ part, float* __restrict__ out) {
    double s = 0.0;
    #pragma unroll
    for (int k = 0; k < NBLK / 256; ++k)
        s += part[threadIdx.x + k * 256];      // coalesced
    #pragma unroll
    for (int off = 32; off > 0; off >>= 1)
        s += __shfl_down(s, off, 64);
    __shared__ double r[4];
    const int lane = threadIdx.x & 63;
    const int wave = threadIdx.x >> 6;
    if (lane == 0) r[wave] = s;
    __syncthreads();
    if (threadIdx.x == 0)
        out[0] = (float)((r[0] + r[1] + r[2] + r[3]) / (double)B_SIZE);
}

extern "C" void kernel_launch(void* const* d_in, const int* in_sizes, int n_in,
                              void* d_out, int out_size, void* d_ws, size_t ws_size,
                              hipStream_t stream) {
    const float* pred       = (const float*)d_in[0];
    const float* gt_boxes   = (const float*)d_in[1];
    const int*   gt_classes = (const int*)d_in[2];
    float* out   = (float*)d_out;
    double* part = (double*)d_ws;   // 1024 doubles; every slot written each launch

    yolo_loss_kernel<<<NBLK, TPB, 0, stream>>>(pred, gt_boxes, gt_classes, part);
    yolo_reduce_kernel<<<1, 256, 0, stream>>>(part, out);
}

// Round 5
// 279.939 us; speedup vs baseline: 1.0168x; 1.0168x over previous
//
#include <hip/hip_runtime.h>

// B=1048576, A=3, N=8, NUM_CLASSES=3, LAMBDA_COORD=5
#define B_SIZE   1048576
#define BPT      4                        // batches per thread
#define NTHREADS (B_SIZE / BPT)           // 262144 threads -> 4096 waves (4x fewer)
#define TPB      256
#define NBLK     (NTHREADS / TPB)         // 1024 blocks

__device__ __forceinline__ float frcp(float x) { return __builtin_amdgcn_rcpf(x); }

__device__ __forceinline__ float anchor_batch_loss(
    const float* __restrict__ pr, const float* __restrict__ gb,
    const int* __restrict__ gc) {
    float total = 0.0f;
    #pragma unroll
    for (int a = 0; a < 3; ++a) {
        const float* p = pr + a * 8;
        const float px = frcp(1.0f + __expf(-p[0]));
        const float py = frcp(1.0f + __expf(-p[1]));
        const float pw = p[2];
        const float ph = p[3];
        const float z  = p[4];
        const float px1 = px - pw * 0.5f, px2 = px + pw * 0.5f;
        const float py1 = py - ph * 0.5f, py2 = py + ph * 0.5f;
        const float pa_eps = (px2 - px1) * (py2 - py1) + 1e-6f;

        float best_iou = -3.4e38f;
        int best_idx = 0;
        #pragma unroll
        for (int n = 0; n < 8; ++n) {
            const float gx = gb[n*4+0], gy = gb[n*4+1];
            const float gw = gb[n*4+2], gh = gb[n*4+3];
            const float hw = gw * 0.5f, hh = gh * 0.5f;
            const float iw = fmaxf(fminf(px2, gx + hw) - fmaxf(px1, gx - hw), 0.0f);
            const float ih = fmaxf(fminf(py2, gy + hh) - fmaxf(py1, gy - hh), 0.0f);
            const float inter = iw * ih;
            const float iou = inter * frcp((pa_eps + gw * gh) - inter);
            const bool upd = iou > best_iou;       // strict > == first-max (argmax)
            best_iou = upd ? iou : best_iou;
            best_idx = upd ? n : best_idx;
        }
        const bool matched = best_iou > 0.5f;

        float mbx = gb[0], mby = gb[1], mbw = gb[2], mbh = gb[3];
        int mcls = gc[0];
        #pragma unroll
        for (int n = 1; n < 8; ++n) {
            const bool s = (best_idx == n);
            mbx = s ? gb[n*4+0] : mbx;
            mby = s ? gb[n*4+1] : mby;
            mbw = s ? gb[n*4+2] : mbw;
            mbh = s ? gb[n*4+3] : mbh;
            mcls = s ? gc[n] : mcls;
        }

        // conf loss via shared softplus (clamped at 100)
        const float az = fabsf(z);
        const float c  = __logf(1.0f + __expf(-az));
        const float sp_pos = fmaxf(z, 0.0f) + c;
        const float sp_neg = fmaxf(-z, 0.0f) + c;
        total += fminf(matched ? sp_neg : sp_pos, 100.0f);

        if (matched) {
            const float dx = px - mbx, dy = py - mby;
            const float dw = pw - mbw, dh = ph - mbh;
            total += 5.0f * (dx*dx + dy*dy + dw*dw + dh*dh);
            const float l0 = p[5], l1 = p[6], l2 = p[7];
            const float m = fmaxf(l0, fmaxf(l1, l2));
            const float lse = m + __logf(__expf(l0-m) + __expf(l1-m) + __expf(l2-m));
            const float sel = (mcls == 0) ? l0 : ((mcls == 1) ? l1 : l2);
            total += lse - sel;
        }
    }
    return total;
}

__global__ __launch_bounds__(TPB) void yolo_loss_kernel(
    const float* __restrict__ pred,       // [B,3,8]  row = 24 floats
    const float* __restrict__ gt_boxes,   // [B,8,4]  row = 32 floats
    const int*   __restrict__ gt_classes, // [B,8]    row = 8 ints
    double* __restrict__ part) {          // [NBLK] per-block partials
    const int gtid = blockIdx.x * TPB + threadIdx.x;

    float total = 0.0f;
    #pragma unroll
    for (int pass = 0; pass < BPT; ++pass) {
        const int b = pass * NTHREADS + gtid;   // grid-stride: covers B exactly

        float pr[24];
        const float4* pv4 = reinterpret_cast<const float4*>(pred + (size_t)b * 24);
        #pragma unroll
        for (int i = 0; i < 6; ++i) reinterpret_cast<float4*>(pr)[i] = pv4[i];

        float gb[32];
        const float4* gv4 = reinterpret_cast<const float4*>(gt_boxes + (size_t)b * 32);
        #pragma unroll
        for (int i = 0; i < 8; ++i) reinterpret_cast<float4*>(gb)[i] = gv4[i];

        int gc[8];
        const int4* gc4 = reinterpret_cast<const int4*>(gt_classes + (size_t)b * 8);
        #pragma unroll
        for (int i = 0; i < 2; ++i) reinterpret_cast<int4*>(gc)[i] = gc4[i];

        total += anchor_batch_loss(pr, gb, gc);
    }

    // ---- wave(64) shuffle reduce -> LDS -> per-block partial store ----
    #pragma unroll
    for (int off = 32; off > 0; off >>= 1)
        total += __shfl_down(total, off, 64);
    __shared__ float smem[TPB / 64];
    const int lane = threadIdx.x & 63;
    const int wid  = threadIdx.x >> 6;
    if (lane == 0) smem[wid] = total;
    __syncthreads();
    if (threadIdx.x == 0) {
        double s = 0.0;
        #pragma unroll
        for (int w = 0; w < TPB / 64; ++w) s += (double)smem[w];
        part[blockIdx.x] = s;
    }
}

__global__ __launch_bounds__(256) void yolo_reduce_kernel(
    const double* __restrict__ part, float* __restrict__ out) {
    double s = 0.0;
    #pragma unroll
    for (int k = 0; k < NBLK / 256; ++k)
        s += part[threadIdx.x + k * 256];      // coalesced
    #pragma unroll
    for (int off = 32; off > 0; off >>= 1)
        s += __shfl_down(s, off, 64);
    __shared__ double r[4];
    const int lane = threadIdx.x & 63;
    const int wave = threadIdx.x >> 6;
    if (lane == 0) r[wave] = s;
    __syncthreads();
    if (threadIdx.x == 0)
        out[0] = (float)((r[0] + r[1] + r[2] + r[3]) / (double)B_SIZE);
}

extern "C" void kernel_launch(void* const* d_in, const int* in_sizes, int n_in,
                              void* d_out, int out_size, void* d_ws, size_t ws_size,
                              hipStream_t stream) {
    const float* pred       = (const float*)d_in[0];
    const float* gt_boxes   = (const float*)d_in[1];
    const int*   gt_classes = (const int*)d_in[2];
    float* out   = (float*)d_out;
    double* part = (double*)d_ws;   // 1024 doubles; every slot written each launch

    yolo_loss_kernel<<<NBLK, TPB, 0, stream>>>(pred, gt_boxes, gt_classes, part);
    yolo_reduce_kernel<<<1, 256, 0, stream>>>(part, out);
}